// Round 11
// baseline (768.440 us; speedup 1.0000x reference)
//
#include <hip/hip_runtime.h>
#include <stdint.h>

// ---------------------------------------------------------------------------
// ResidueGraphModel: aanet_proj (512->1024->1024->512->80, ReLU) -> in_net
// (80->512) -> GIN sum-aggregation + MLP (512->512->512) -> out_net (512->80).
// R19: (a) revert L2 to the 128^2+(256,4) body -- third 8-phase attempt
// measured 157.6us @ 27% MfmaUtil vs 122us @ 37% (structure final; no more
// schedule bets). (b) fuse aggregation + L5: each block gathers its 128-row
// s-tile ONCE into swizzled LDS (write pattern = GEMM A-layout, 32-bank
// conflict-free), then runs the K=128 GEMM over all 4 col-blocks from LDS.
// Removes s materialization (13MB write + 51MB 4x re-read) + one dispatch;
// gather work unchanged; bf16 rounding points identical. Buffers: g->bufB,
// r1->bufA, g2->bufC (pf/bufA only read before bufA is rewritten).
// R17 (kept): 64x128 body for L4/L8; preprocess grain. R16 (kept):
// atomic-free scatter via persisted rank[e], trailing in L1's dispatch.
// Invariants: XOR-swizzled LDS (0 bank conflicts), operand-swapped MFMA
// (packed 8B C stores), XCD-grouped decode, row-padded A buffers.
// Outputs fp32: d_out = [peptide_mask (N*80) | peptide_feat (N*80)].
// ---------------------------------------------------------------------------

using bf16x8 = __attribute__((ext_vector_type(8))) short;
using f32x4  = __attribute__((ext_vector_type(4))) float;

__device__ inline unsigned short f2bf(float f) {
    union { float f; unsigned u; } v; v.f = f;
    unsigned u = v.u;
    u += 0x7FFFu + ((u >> 16) & 1u);   // RNE
    return (unsigned short)(u >> 16);
}
__device__ inline float bf2f(unsigned u16) {
    return __uint_as_float(u16 << 16);
}

// ------------- merged preprocessing ----------------------------------------
struct PreDescs {
    const float* W[8]; unsigned short* Wt[8];
    int K[8], M[8], Kp[8], ntx[8], start[8];
    int tEnd, cEnd, eEnd;
    const float* feat; unsigned short* featb; int nFeat;
    const int* ei; int E; int* cnt; int* rank;
};

__global__ __launch_bounds__(256) void rg_preprocess(PreDescs d) {
    int b = blockIdx.x;
    int tid = threadIdx.x;
    if (b < d.tEnd) {
        __shared__ float t[32][33];
        int di = 0;
#pragma unroll
        for (int i = 1; i < 8; ++i) if (b >= d.start[i]) di = i;
        int local = b - d.start[di];
        int bx = local % d.ntx[di];
        int by = local / d.ntx[di];
        const float* W = d.W[di];
        unsigned short* Wt = d.Wt[di];
        int K = d.K[di], M = d.M[di], Kp = d.Kp[di];
        int mb = bx * 32, kb = by * 32;
        int tx = tid & 31, tg = tid >> 5;
#pragma unroll
        for (int p = 0; p < 4; ++p) {
            int r = tg + p * 8;
            int k = kb + r, m = mb + tx;
            t[r][tx] = (k < K && m < M) ? W[(size_t)k * M + m] : 0.f;
        }
        __syncthreads();
#pragma unroll
        for (int p = 0; p < 4; ++p) {
            int r = tg + p * 8;
            int mo = mb + r, ko = kb + tx;
            Wt[(size_t)mo * Kp + ko] = f2bf(t[tx][r]);
        }
    } else if (b < d.cEnd) {
        int base = (b - d.tEnd) * 4096 + tid * 4;   // 16 elems/thread
#pragma unroll
        for (int p = 0; p < 4; ++p) {
            int i = base + p * 1024;
            if (i + 3 < d.nFeat) {
                float4 v = *(const float4*)(d.feat + i);
                ushort4 o; o.x = f2bf(v.x); o.y = f2bf(v.y); o.z = f2bf(v.z); o.w = f2bf(v.w);
                *(ushort4*)(d.featb + i) = o;
            }
        }
    } else {
        int e0 = (b - d.cEnd) * 1024 + tid;         // 4 edges/thread
#pragma unroll
        for (int p = 0; p < 4; ++p) {
            int e = e0 + p * 256;
            if (e < d.E) {
                int dd = d.ei[d.E + e];
                d.rank[e] = atomicAdd(&d.cnt[dd], 1);
            }
        }
    }
}

// ---------------- 128x128 GEMM body (single-buffer) -------------------------
template <bool RELU, bool OUT_BF, bool OUT_F32, bool DEGB, int MT>
__device__ __forceinline__ void gemm_body(
    int bid,
    const unsigned short* __restrict__ A, const unsigned short* __restrict__ Bt,
    const float* __restrict__ bias, const int* __restrict__ deg, int Mvalid,
    unsigned short* __restrict__ outB, float* __restrict__ outF,
    int Nrows, int Kp, int Mp, int gN)
{
    __shared__ __align__(16) unsigned short As[128 * 64];
    __shared__ __align__(16) unsigned short Bs[128 * 64];

    int xcd = bid & 7;
    int slot = bid >> 3;
    int c = slot % MT;
    int rsub = slot / MT;
    int rt = rsub * 8 + xcd;
    if (rt >= gN) return;
    const int rowBase = rt * 128;
    const int nBase   = c * 128;

    const int tid  = threadIdx.x;
    const int lane = tid & 63;
    const int w    = tid >> 6;
    const int wm   = w & 1, wn = w >> 1;

    f32x4 acc[4][4];
#pragma unroll
    for (int i = 0; i < 4; ++i)
#pragma unroll
        for (int j = 0; j < 4; ++j) acc[i][j] = (f32x4){0.f, 0.f, 0.f, 0.f};

    const int nkt = Kp >> 6;
    for (int kt = 0; kt < nkt; ++kt) {
        __syncthreads();
        const int k0 = kt * 64;
#pragma unroll
        for (int i = 0; i < 4; ++i) {
            int q   = i * 256 + tid;
            int r   = q >> 3;
            int cbg = (q & 7) ^ (r & 7);
            const unsigned short* gp = A + (size_t)(rowBase + r) * Kp + k0 + cbg * 8;
            __builtin_amdgcn_global_load_lds(
                (const __attribute__((address_space(1))) void*)gp,
                (__attribute__((address_space(3))) void*)(&As[q * 8]), 16, 0, 0);
        }
#pragma unroll
        for (int i = 0; i < 4; ++i) {
            int q   = i * 256 + tid;
            int r   = q >> 3;
            int cbg = (q & 7) ^ (r & 7);
            const unsigned short* gp = Bt + (size_t)(nBase + r) * Kp + k0 + cbg * 8;
            __builtin_amdgcn_global_load_lds(
                (const __attribute__((address_space(1))) void*)gp,
                (__attribute__((address_space(3))) void*)(&Bs[q * 8]), 16, 0, 0);
        }
        __syncthreads();
#pragma unroll
        for (int kk = 0; kk < 2; ++kk) {
            bf16x8 a[4], b[4];
            const int cb = kk * 4 + (lane >> 4);
#pragma unroll
            for (int i = 0; i < 4; ++i) {
                int r = wm * 64 + i * 16 + (lane & 15);
                a[i] = *(const bf16x8*)&As[(r * 8 + (cb ^ (r & 7))) * 8];
            }
#pragma unroll
            for (int j = 0; j < 4; ++j) {
                int r = wn * 64 + j * 16 + (lane & 15);
                b[j] = *(const bf16x8*)&Bs[(r * 8 + (cb ^ (r & 7))) * 8];
            }
#pragma unroll
            for (int i = 0; i < 4; ++i)
#pragma unroll
                for (int j = 0; j < 4; ++j)
                    acc[i][j] = __builtin_amdgcn_mfma_f32_16x16x32_bf16(b[j], a[i], acc[i][j], 0, 0, 0);
        }
    }

    const int quad = lane >> 4;
#pragma unroll
    for (int i = 0; i < 4; ++i) {
        int row = rowBase + wm * 64 + i * 16 + (lane & 15);
        if (row >= Nrows) continue;
        float sc = 1.f;
        if (DEGB) sc = 1.f + (float)deg[row];
#pragma unroll
        for (int j = 0; j < 4; ++j) {
            int colb = nBase + wn * 64 + j * 16 + quad * 4;
            float4 bv = (colb < Mvalid) ? *(const float4*)(bias + colb)
                                        : (float4){0.f, 0.f, 0.f, 0.f};
            float v0 = acc[i][j][0] + sc * bv.x;
            float v1 = acc[i][j][1] + sc * bv.y;
            float v2 = acc[i][j][2] + sc * bv.z;
            float v3 = acc[i][j][3] + sc * bv.w;
            if (RELU) {
                v0 = v0 > 0.f ? v0 : 0.f; v1 = v1 > 0.f ? v1 : 0.f;
                v2 = v2 > 0.f ? v2 : 0.f; v3 = v3 > 0.f ? v3 : 0.f;
            }
            if (OUT_BF) {
                ushort4 o; o.x = f2bf(v0); o.y = f2bf(v1); o.z = f2bf(v2); o.w = f2bf(v3);
                *(ushort4*)(outB + (size_t)row * Mp + colb) = o;
            }
            if (OUT_F32) {
                if (colb < Mvalid)
                    *(float4*)(outF + (size_t)row * Mvalid + colb) = (float4){v0, v1, v2, v3};
            }
        }
    }
}

template <bool RELU, bool OUT_BF, bool OUT_F32, bool DEGB, int MT>
__global__ __launch_bounds__(256, 4) void rg_gemm(
    const unsigned short* __restrict__ A, const unsigned short* __restrict__ Bt,
    const float* __restrict__ bias, const int* __restrict__ deg, int Mvalid,
    unsigned short* __restrict__ outB, float* __restrict__ outF,
    int Nrows, int Kp, int Mp, int gN)
{
    gemm_body<RELU, OUT_BF, OUT_F32, DEGB, MT>(blockIdx.x, A, Bt, bias, deg,
                                               Mvalid, outB, outF, Nrows, Kp, Mp, gN);
}

// ---------------- 64x128 GEMM body (M=128 latency-bound layers) -------------
template <bool RELU, bool OUT_BF, bool OUT_F32, int MT>
__global__ __launch_bounds__(256, 4) void rg_gemm64(
    const unsigned short* __restrict__ A, const unsigned short* __restrict__ Bt,
    const float* __restrict__ bias, int Mvalid,
    unsigned short* __restrict__ outB, float* __restrict__ outF,
    int Nrows, int Kp, int Mp, int gN64)
{
    __shared__ __align__(16) unsigned short As[64 * 64];
    __shared__ __align__(16) unsigned short Bs[128 * 64];

    int bid = blockIdx.x;
    int xcd = bid & 7;
    int slot = bid >> 3;
    int c = slot % MT;
    int rsub = slot / MT;
    int rt = rsub * 8 + xcd;
    if (rt >= gN64) return;
    const int rowBase = rt * 64;
    const int nBase   = c * 128;

    const int tid  = threadIdx.x;
    const int lane = tid & 63;
    const int wn   = tid >> 6;

    f32x4 acc[4][2];
#pragma unroll
    for (int i = 0; i < 4; ++i)
#pragma unroll
        for (int j = 0; j < 2; ++j) acc[i][j] = (f32x4){0.f, 0.f, 0.f, 0.f};

    const int nkt = Kp >> 6;
    for (int kt = 0; kt < nkt; ++kt) {
        __syncthreads();
        const int k0 = kt * 64;
#pragma unroll
        for (int i = 0; i < 2; ++i) {
            int q   = i * 256 + tid;
            int r   = q >> 3;
            int cbg = (q & 7) ^ (r & 7);
            const unsigned short* gp = A + (size_t)(rowBase + r) * Kp + k0 + cbg * 8;
            __builtin_amdgcn_global_load_lds(
                (const __attribute__((address_space(1))) void*)gp,
                (__attribute__((address_space(3))) void*)(&As[q * 8]), 16, 0, 0);
        }
#pragma unroll
        for (int i = 0; i < 4; ++i) {
            int q   = i * 256 + tid;
            int r   = q >> 3;
            int cbg = (q & 7) ^ (r & 7);
            const unsigned short* gp = Bt + (size_t)(nBase + r) * Kp + k0 + cbg * 8;
            __builtin_amdgcn_global_load_lds(
                (const __attribute__((address_space(1))) void*)gp,
                (__attribute__((address_space(3))) void*)(&Bs[q * 8]), 16, 0, 0);
        }
        __syncthreads();
#pragma unroll
        for (int kk = 0; kk < 2; ++kk) {
            bf16x8 a[4], b[2];
            const int cb = kk * 4 + (lane >> 4);
#pragma unroll
            for (int i = 0; i < 4; ++i) {
                int r = i * 16 + (lane & 15);
                a[i] = *(const bf16x8*)&As[(r * 8 + (cb ^ (r & 7))) * 8];
            }
#pragma unroll
            for (int j = 0; j < 2; ++j) {
                int r = wn * 32 + j * 16 + (lane & 15);
                b[j] = *(const bf16x8*)&Bs[(r * 8 + (cb ^ (r & 7))) * 8];
            }
#pragma unroll
            for (int i = 0; i < 4; ++i)
#pragma unroll
                for (int j = 0; j < 2; ++j)
                    acc[i][j] = __builtin_amdgcn_mfma_f32_16x16x32_bf16(b[j], a[i], acc[i][j], 0, 0, 0);
        }
    }

    const int quad = lane >> 4;
#pragma unroll
    for (int i = 0; i < 4; ++i) {
        int row = rowBase + i * 16 + (lane & 15);
        if (row >= Nrows) continue;
#pragma unroll
        for (int j = 0; j < 2; ++j) {
            int colb = nBase + wn * 32 + j * 16 + quad * 4;
            float4 bv = (colb < Mvalid) ? *(const float4*)(bias + colb)
                                        : (float4){0.f, 0.f, 0.f, 0.f};
            float v0 = acc[i][j][0] + bv.x;
            float v1 = acc[i][j][1] + bv.y;
            float v2 = acc[i][j][2] + bv.z;
            float v3 = acc[i][j][3] + bv.w;
            if (RELU) {
                v0 = v0 > 0.f ? v0 : 0.f; v1 = v1 > 0.f ? v1 : 0.f;
                v2 = v2 > 0.f ? v2 : 0.f; v3 = v3 > 0.f ? v3 : 0.f;
            }
            if (OUT_BF) {
                ushort4 o; o.x = f2bf(v0); o.y = f2bf(v1); o.z = f2bf(v2); o.w = f2bf(v3);
                *(ushort4*)(outB + (size_t)row * Mp + colb) = o;
            }
            if (OUT_F32) {
                if (colb < Mvalid)
                    *(float4*)(outF + (size_t)row * Mvalid + colb) = (float4){v0, v1, v2, v3};
            }
        }
    }
}

// ---------------- fused aggregation + L5 GEMM (R19) -------------------------
// Per block: gather s-tile [128 rows x 128 cols] bf16 into LDS once
// (s[i] = pf[i] + sum_{src->i} pf[src]; swizzled exactly like the GEMM
// A-buffer: chunk cbg of local row lr lands at slot lr*8 + (cbg^(lr&7))),
// then g = s @ Win + (1+deg)*bin over 4 col-blocks of 128 reusing the tile.
// LDS write: lane l -> uint (q*4 + (lc&3)); per half-wave a bijection onto a
// row's 32 uints -> 2 lanes/bank across the wave (free, m136).
__global__ __launch_bounds__(256, 4) void rg_agg_gemm_l5(
    const unsigned short* __restrict__ pf,     // [Npad,128] bf16
    const int* __restrict__ rowptr, const int* __restrict__ cols,
    const unsigned short* __restrict__ Bt,     // Wit [512][128] bf16
    const float* __restrict__ bias, const int* __restrict__ deg,
    unsigned short* __restrict__ outB,         // g [Npad,512] bf16
    int Nn, int gN)
{
    __shared__ __align__(16) unsigned short AsK[2][128 * 64];  // K-tiles 0/1
    __shared__ __align__(16) unsigned short Bs[128 * 64];

    int bid = blockIdx.x;
    int xcd = bid & 7;
    int rsub = bid >> 3;
    int rt = rsub * 8 + xcd;
    if (rt >= gN) return;
    const int rowBase = rt * 128;

    const int tid  = threadIdx.x;
    const int lane = tid & 63;
    const int w    = tid >> 6;

    // ---- phase 1: gather; wave w covers block-local rows [w*32, +32) ----
    {
        const unsigned* xp = (const unsigned*)pf;
        const int t    = lane >> 5;     // K-tile (cols 0..63 / 64..127)
        const int lc   = lane & 31;     // uint index within K-tile row
        const int cbg  = lc >> 2;       // 16B chunk within K-tile row
        const int upos = lc & 3;        // uint within chunk
        for (int rr = 0; rr < 32; ++rr) {
            int lr = w * 32 + rr;
            int node = rowBase + lr;
            if (node < Nn) {
                size_t off = (size_t)node * 64 + lane;
                unsigned u = xp[off];
                float a0 = bf2f(u & 0xffffu), a1 = bf2f(u >> 16);
                int beg = rowptr[node], end = rowptr[node + 1];
                int e = beg;
                for (; e + 8 <= end; e += 8) {
                    unsigned v[8];
#pragma unroll
                    for (int p = 0; p < 8; ++p) v[p] = xp[(size_t)cols[e + p] * 64 + lane];
#pragma unroll
                    for (int p = 0; p < 8; ++p) { a0 += bf2f(v[p] & 0xffffu); a1 += bf2f(v[p] >> 16); }
                }
                for (; e < end; ++e) {
                    unsigned v = xp[(size_t)cols[e] * 64 + lane];
                    a0 += bf2f(v & 0xffffu); a1 += bf2f(v >> 16);
                }
                unsigned o = (unsigned)f2bf(a0) | ((unsigned)f2bf(a1) << 16);
                int q = lr * 8 + (cbg ^ (lr & 7));
                ((unsigned*)AsK[t])[q * 4 + upos] = o;
            }
        }
    }
    __syncthreads();

    // ---- phase 2: K=128 GEMM over 4 col-blocks, A-tile from LDS ----
    const int wm = w & 1, wn = w >> 1;
    const int quad = lane >> 4;
    for (int c = 0; c < 4; ++c) {
        f32x4 acc[4][4];
#pragma unroll
        for (int i = 0; i < 4; ++i)
#pragma unroll
            for (int j = 0; j < 4; ++j) acc[i][j] = (f32x4){0.f, 0.f, 0.f, 0.f};

#pragma unroll
        for (int kt = 0; kt < 2; ++kt) {
            __syncthreads();            // protect Bs from previous reads
            const int k0 = kt * 64;
#pragma unroll
            for (int i = 0; i < 4; ++i) {
                int q   = i * 256 + tid;
                int r   = q >> 3;
                int cb2 = (q & 7) ^ (r & 7);
                const unsigned short* gp = Bt + (size_t)(c * 128 + r) * 128 + k0 + cb2 * 8;
                __builtin_amdgcn_global_load_lds(
                    (const __attribute__((address_space(1))) void*)gp,
                    (__attribute__((address_space(3))) void*)(&Bs[q * 8]), 16, 0, 0);
            }
            __syncthreads();
#pragma unroll
            for (int kk = 0; kk < 2; ++kk) {
                bf16x8 a[4], b[4];
                const int cb = kk * 4 + (lane >> 4);
#pragma unroll
                for (int i = 0; i < 4; ++i) {
                    int r = wm * 64 + i * 16 + (lane & 15);
                    a[i] = *(const bf16x8*)&AsK[kt][(r * 8 + (cb ^ (r & 7))) * 8];
                }
#pragma unroll
                for (int j = 0; j < 4; ++j) {
                    int r = wn * 64 + j * 16 + (lane & 15);
                    b[j] = *(const bf16x8*)&Bs[(r * 8 + (cb ^ (r & 7))) * 8];
                }
#pragma unroll
                for (int i = 0; i < 4; ++i)
#pragma unroll
                    for (int j = 0; j < 4; ++j)
                        acc[i][j] = __builtin_amdgcn_mfma_f32_16x16x32_bf16(b[j], a[i], acc[i][j], 0, 0, 0);
            }
        }

        // epilogue for col-block c: g = acc + (1+deg)*bin
#pragma unroll
        for (int i = 0; i < 4; ++i) {
            int row = rowBase + wm * 64 + i * 16 + (lane & 15);
            if (row >= Nn) continue;
            float sc = 1.f + (float)deg[row];
#pragma unroll
            for (int j = 0; j < 4; ++j) {
                int colb = c * 128 + wn * 64 + j * 16 + quad * 4;
                float4 bv = *(const float4*)(bias + colb);
                float v0 = acc[i][j][0] + sc * bv.x;
                float v1 = acc[i][j][1] + sc * bv.y;
                float v2 = acc[i][j][2] + sc * bv.z;
                float v3 = acc[i][j][3] + sc * bv.w;
                ushort4 o; o.x = f2bf(v0); o.y = f2bf(v1); o.z = f2bf(v2); o.w = f2bf(v3);
                *(ushort4*)(outB + (size_t)row * 512 + colb) = o;
            }
        }
    }
}

// L1 GEMM + edge scatter in one dispatch (trailing layout, atomic-free)
__global__ __launch_bounds__(256, 4) void rg_gemm_l1_scatter(
    const unsigned short* __restrict__ A, const unsigned short* __restrict__ Bt,
    const float* __restrict__ bias, int Mvalid,
    unsigned short* __restrict__ outB, int Nrows, int Kp, int Mp, int gN,
    int gemmBlocks, const int* __restrict__ ei, int E,
    const int* __restrict__ rowptr, const int* __restrict__ rank,
    int* __restrict__ cols)
{
    int bid = blockIdx.x;
    if (bid < gemmBlocks) {
        gemm_body<true, true, false, false, 8>(bid, A, Bt, bias, nullptr,
                                               Mvalid, outB, nullptr, Nrows, Kp, Mp, gN);
    } else {
        int e = (bid - gemmBlocks) * 256 + threadIdx.x;
        if (e < E) {
            int d = ei[E + e];
            int p = rowptr[d] + rank[e];
            cols[p] = ei[e];
        }
    }
}

// ---------------- merged scan ------------------------------------------------
__device__ __forceinline__ void rg_gridbar(int* bar, int nb, int phase) {
    __syncthreads();
    if (threadIdx.x == 0) {
        __threadfence();
        atomicAdd(bar, 1);
        int target = phase * nb;
        while (__hip_atomic_load(bar, __ATOMIC_RELAXED, __HIP_MEMORY_SCOPE_AGENT) < target) {}
        __threadfence();
    }
    __syncthreads();
}

__global__ __launch_bounds__(1024) void rg_scan_all(
    const int* __restrict__ cnt, int* __restrict__ rowptr,
    int* __restrict__ bsums, int* bar, int Nn, int E, int nb)
{
    __shared__ int sd[1024];
    const int tid = threadIdx.x;
    const int bid = blockIdx.x;
    const int i   = bid * 1024 + tid;

    int v = (i < Nn) ? cnt[i] : 0;
    sd[tid] = v;
    __syncthreads();
    for (int off = 1; off < 1024; off <<= 1) {
        int t = (tid >= off) ? sd[tid - off] : 0;
        __syncthreads();
        sd[tid] += t;
        __syncthreads();
    }
    if (tid == 1023) bsums[bid] = sd[1023];
    rg_gridbar(bar, nb, 1);

    if (bid == 0 && tid < 64) {
        int bv = (tid < nb) ? bsums[tid] : 0;
        int incl = bv;
#pragma unroll
        for (int off = 1; off < 64; off <<= 1) {
            int t = __shfl_up(incl, off, 64);
            if (tid >= off) incl += t;
        }
        if (tid < nb) bsums[tid] = incl - bv;
    }
    rg_gridbar(bar, nb, 2);

    if (i < Nn) {
        int ex = sd[tid] - v + bsums[bid];
        rowptr[i] = ex;
    }
    if (i == 0) rowptr[Nn] = E;
}

// ---------------------------------------------------------------------------
extern "C" void kernel_launch(void* const* d_in, const int* in_sizes, int n_in,
                              void* d_out, int out_size, void* d_ws, size_t ws_size,
                              hipStream_t stream)
{
    const float* feat = (const float*)d_in[0];
    const int*   ei   = (const int*)d_in[1];
    const float* W1 = (const float*)d_in[2];  const float* b1 = (const float*)d_in[3];
    const float* W2 = (const float*)d_in[4];  const float* b2 = (const float*)d_in[5];
    const float* W3 = (const float*)d_in[6];  const float* b3 = (const float*)d_in[7];
    const float* W4 = (const float*)d_in[8];  const float* b4 = (const float*)d_in[9];
    const float* Wi = (const float*)d_in[10]; const float* bi = (const float*)d_in[11];
    const float* Wg1 = (const float*)d_in[12]; const float* bg1 = (const float*)d_in[13];
    const float* Wg2 = (const float*)d_in[14]; const float* bg2 = (const float*)d_in[15];
    const float* Wo = (const float*)d_in[16]; const float* bo = (const float*)d_in[17];

    const int N = in_sizes[0] / 512;   // 50000
    const int E = in_sizes[1] / 2;     // 800000
    const int gN = (N + 127) / 128;    // 391
    const int Npad = gN * 128;         // 50048

    char* ws = (char*)d_ws;
    size_t o = 0;
    auto alloc = [&](size_t bytes) { char* p = ws + o; o += (bytes + 255) & ~(size_t)255; return p; };
    unsigned short* bufA = (unsigned short*)alloc((size_t)Npad * 1024 * 2); // h1 / pf / r1
    unsigned short* bufB = (unsigned short*)alloc((size_t)Npad * 1024 * 2); // h2 / g
    unsigned short* bufC = (unsigned short*)alloc((size_t)Npad * 512 * 2);  // A0 / h3 / g2
    unsigned short* W1t = (unsigned short*)alloc((size_t)1024 * 512 * 2);
    unsigned short* W2t = (unsigned short*)alloc((size_t)1024 * 1024 * 2);
    unsigned short* W3t = (unsigned short*)alloc((size_t)512 * 1024 * 2);
    unsigned short* W4t = (unsigned short*)alloc((size_t)128 * 512 * 2);
    unsigned short* Wit = (unsigned short*)alloc((size_t)512 * 128 * 2);
    unsigned short* Wg1t = (unsigned short*)alloc((size_t)512 * 512 * 2);
    unsigned short* Wg2t = (unsigned short*)alloc((size_t)512 * 512 * 2);
    unsigned short* Wot = (unsigned short*)alloc((size_t)128 * 512 * 2);
    int* cnt    = (int*)alloc((size_t)(N + 64) * 4);
    int* bar    = cnt + N;
    int* rowptr = (int*)alloc((size_t)(N + 1) * 4);
    int* rank   = (int*)alloc((size_t)E * 4);
    int* cols   = (int*)alloc((size_t)E * 4);
    int* bsums  = (int*)alloc(256);

    float* out_mask = (float*)d_out;                  // [N,80]
    float* out_feat = (float*)d_out + (size_t)N * 80; // [N,80]

    // ---- merged preprocessing ----
    hipMemsetAsync(cnt, 0, (size_t)(N + 64) * 4, stream);
    {
        PreDescs d;
        const float* Ws[8]  = {W1, W2, W3, W4, Wi, Wg1, Wg2, Wo};
        unsigned short* Ts[8] = {W1t, W2t, W3t, W4t, Wit, Wg1t, Wg2t, Wot};
        int Ks[8]  = {512, 1024, 1024, 512, 80, 512, 512, 512};
        int Ms[8]  = {1024, 1024, 512, 80, 512, 512, 512, 80};
        int Kps[8] = {512, 1024, 1024, 512, 128, 512, 512, 512};
        int Mps[8] = {1024, 1024, 512, 128, 512, 512, 512, 128};
        int st = 0;
        for (int i = 0; i < 8; ++i) {
            d.W[i] = Ws[i]; d.Wt[i] = Ts[i];
            d.K[i] = Ks[i]; d.M[i] = Ms[i]; d.Kp[i] = Kps[i];
            d.ntx[i] = Mps[i] / 32;
            d.start[i] = st;
            st += (Mps[i] / 32) * (Kps[i] / 32);
        }
        d.tEnd = st;
        d.cEnd = st + (N * 512) / 4096;
        d.eEnd = d.cEnd + (E + 1023) / 1024;
        d.feat = feat; d.featb = bufC; d.nFeat = N * 512;
        d.ei = ei; d.E = E; d.cnt = cnt; d.rank = rank;
        rg_preprocess<<<d.eEnd, 256, 0, stream>>>(d);
    }

    // ---- CSR scan ----
    const int nb = (N + 1023) / 1024;   // 49
    rg_scan_all<<<nb, 1024, 0, stream>>>(cnt, rowptr, bsums, bar, N, E, nb);

    const int rg8 = ((gN + 7) / 8) * 8;      // 392
    auto grid = [&](int MT) { return dim3(rg8 * MT); };
    const int gN64 = (N + 63) / 64;          // 782
    const int rg64 = ((gN64 + 7) / 8) * 8;   // 784

    // L1: h1 = relu(A0 @ W1 + b1)   [N,1024]  + atomic-free scatter trailing
    {
        const int gemmBlocks = rg8 * 8;             // 3136
        const int scatBlocks = (E + 255) / 256;     // 3125
        rg_gemm_l1_scatter<<<dim3(gemmBlocks + scatBlocks), 256, 0, stream>>>(
            bufC, W1t, b1, 1024, bufA, N, 512, 1024, gN,
            gemmBlocks, ei, E, rowptr, rank, cols);
    }

    // L2: h2 = relu(h1 @ W2 + b2)   [N,1024]   (128^2 MT=8, proven winner)
    rg_gemm<true, true, false, false, 8><<<grid(8), 256, 0, stream>>>(bufA, W2t, b2, nullptr, 1024, bufB, nullptr, N, 1024, 1024, gN);
    // L3: h3 = relu(h2 @ W3 + b3)   [N,512]
    rg_gemm<true, true, false, false, 4><<<grid(4), 256, 0, stream>>>(bufB, W3t, b3, nullptr, 512, bufC, nullptr, N, 1024, 512, gN);
    // L4: pf = h3 @ W4 + b4  -> fp32 out_feat + bf16 padded [N,128]  (64-row)
    rg_gemm64<false, true, true, 1><<<dim3(rg64), 256, 0, stream>>>(bufC, W4t, b4, 80, bufA, out_feat, N, 512, 128, gN64);

    // fused agg + L5: g = (pf + segsum(pf[src])) @ Win + (1+deg)*bin -> bufB
    rg_agg_gemm_l5<<<dim3(rg8), 256, 0, stream>>>(bufA, rowptr, cols, Wit, bi, cnt, bufB, N, gN);

    // L6: r1 = relu(g @ Wg1 + bg1)  [N,512]   (bufB -> bufA)
    rg_gemm<true, true, false, false, 4><<<grid(4), 256, 0, stream>>>(bufB, Wg1t, bg1, nullptr, 512, bufA, nullptr, N, 512, 512, gN);
    // L7: g2 = r1 @ Wg2 + bg2       [N,512]   (bufA -> bufC)
    rg_gemm<false, true, false, false, 4><<<grid(4), 256, 0, stream>>>(bufA, Wg2t, bg2, nullptr, 512, bufC, nullptr, N, 512, 512, gN);
    // L8: mask = g2 @ Wout + bout -> fp32 out_mask   (64-row)
    rg_gemm64<false, false, true, 1><<<dim3(rg64), 256, 0, stream>>>(bufC, Wot, bo, 80, nullptr, out_mask, N, 512, 128, gN64);
}

// Round 12
// 690.057 us; speedup vs baseline: 1.1136x; 1.1136x over previous
//
#include <hip/hip_runtime.h>
#include <stdint.h>

// ---------------------------------------------------------------------------
// ResidueGraphModel: aanet_proj (512->1024->1024->512->80, ReLU) -> in_net
// (80->512) -> GIN sum-aggregation + MLP (512->512->512) -> out_net (512->80).
// R20: revert R19's agg+L5 fusion (measured 138us @ 1.8% MfmaUtil -- gather
// TLP collapsed from 12500 blocks to 392; latency exposure cost ~75us vs
// ~20us traffic saved). Back to separate agg80 + L5, plus three small wins:
//  (1) agg80 lane-masking: pf cols 80..127 are zeros -> gather loads masked
//      to lanes 0..39 (4->3 cache lines per edge, ~25% of gather traffic);
//      writes keep 64 lanes (s cols 80..127 zeroed). Numerics identical.
//  (2) L5 moved to the 64-row body with DEGB (K=128 = 2 K-tiles is pure
//      latency; 784->3136 blocks doubles wave-level hiding -- same
//      mechanism as R17's L4/L8 win).
//  (3) scan stage-1 via wave shuffles (20 barriers -> 2).
// R17 (kept): 64x128 body for L4/L8; preprocess grain. R16 (kept): atomic-
// free scatter via persisted rank[e], trailing in L1's dispatch. R14 (kept):
// 128^2 single-buffer + __launch_bounds__(256,4) GEMM body (L2 = 122us @
// 37% MfmaUtil = the 2-barrier structure's ceiling; 8-phase attempts 0/3,
// structure final).
// Invariants: XOR-swizzled LDS (0 bank conflicts), operand-swapped MFMA
// (packed 8B C stores), XCD-grouped decode, row-padded A buffers.
// Outputs fp32: d_out = [peptide_mask (N*80) | peptide_feat (N*80)].
// ---------------------------------------------------------------------------

using bf16x8 = __attribute__((ext_vector_type(8))) short;
using f32x4  = __attribute__((ext_vector_type(4))) float;

__device__ inline unsigned short f2bf(float f) {
    union { float f; unsigned u; } v; v.f = f;
    unsigned u = v.u;
    u += 0x7FFFu + ((u >> 16) & 1u);   // RNE
    return (unsigned short)(u >> 16);
}
__device__ inline float bf2f(unsigned u16) {
    return __uint_as_float(u16 << 16);
}

// ------------- merged preprocessing ----------------------------------------
struct PreDescs {
    const float* W[8]; unsigned short* Wt[8];
    int K[8], M[8], Kp[8], ntx[8], start[8];
    int tEnd, cEnd, eEnd;
    const float* feat; unsigned short* featb; int nFeat;
    const int* ei; int E; int* cnt; int* rank;
};

__global__ __launch_bounds__(256) void rg_preprocess(PreDescs d) {
    int b = blockIdx.x;
    int tid = threadIdx.x;
    if (b < d.tEnd) {
        __shared__ float t[32][33];
        int di = 0;
#pragma unroll
        for (int i = 1; i < 8; ++i) if (b >= d.start[i]) di = i;
        int local = b - d.start[di];
        int bx = local % d.ntx[di];
        int by = local / d.ntx[di];
        const float* W = d.W[di];
        unsigned short* Wt = d.Wt[di];
        int K = d.K[di], M = d.M[di], Kp = d.Kp[di];
        int mb = bx * 32, kb = by * 32;
        int tx = tid & 31, tg = tid >> 5;
#pragma unroll
        for (int p = 0; p < 4; ++p) {
            int r = tg + p * 8;
            int k = kb + r, m = mb + tx;
            t[r][tx] = (k < K && m < M) ? W[(size_t)k * M + m] : 0.f;
        }
        __syncthreads();
#pragma unroll
        for (int p = 0; p < 4; ++p) {
            int r = tg + p * 8;
            int mo = mb + r, ko = kb + tx;
            Wt[(size_t)mo * Kp + ko] = f2bf(t[tx][r]);
        }
    } else if (b < d.cEnd) {
        int base = (b - d.tEnd) * 4096 + tid * 4;   // 16 elems/thread
#pragma unroll
        for (int p = 0; p < 4; ++p) {
            int i = base + p * 1024;
            if (i + 3 < d.nFeat) {
                float4 v = *(const float4*)(d.feat + i);
                ushort4 o; o.x = f2bf(v.x); o.y = f2bf(v.y); o.z = f2bf(v.z); o.w = f2bf(v.w);
                *(ushort4*)(d.featb + i) = o;
            }
        }
    } else {
        int e0 = (b - d.cEnd) * 1024 + tid;         // 4 edges/thread
#pragma unroll
        for (int p = 0; p < 4; ++p) {
            int e = e0 + p * 256;
            if (e < d.E) {
                int dd = d.ei[d.E + e];
                d.rank[e] = atomicAdd(&d.cnt[dd], 1);
            }
        }
    }
}

// ---------------- 128x128 GEMM body (single-buffer) -------------------------
template <bool RELU, bool OUT_BF, bool OUT_F32, bool DEGB, int MT>
__device__ __forceinline__ void gemm_body(
    int bid,
    const unsigned short* __restrict__ A, const unsigned short* __restrict__ Bt,
    const float* __restrict__ bias, const int* __restrict__ deg, int Mvalid,
    unsigned short* __restrict__ outB, float* __restrict__ outF,
    int Nrows, int Kp, int Mp, int gN)
{
    __shared__ __align__(16) unsigned short As[128 * 64];
    __shared__ __align__(16) unsigned short Bs[128 * 64];

    int xcd = bid & 7;
    int slot = bid >> 3;
    int c = slot % MT;
    int rsub = slot / MT;
    int rt = rsub * 8 + xcd;
    if (rt >= gN) return;
    const int rowBase = rt * 128;
    const int nBase   = c * 128;

    const int tid  = threadIdx.x;
    const int lane = tid & 63;
    const int w    = tid >> 6;
    const int wm   = w & 1, wn = w >> 1;

    f32x4 acc[4][4];
#pragma unroll
    for (int i = 0; i < 4; ++i)
#pragma unroll
        for (int j = 0; j < 4; ++j) acc[i][j] = (f32x4){0.f, 0.f, 0.f, 0.f};

    const int nkt = Kp >> 6;
    for (int kt = 0; kt < nkt; ++kt) {
        __syncthreads();
        const int k0 = kt * 64;
#pragma unroll
        for (int i = 0; i < 4; ++i) {
            int q   = i * 256 + tid;
            int r   = q >> 3;
            int cbg = (q & 7) ^ (r & 7);
            const unsigned short* gp = A + (size_t)(rowBase + r) * Kp + k0 + cbg * 8;
            __builtin_amdgcn_global_load_lds(
                (const __attribute__((address_space(1))) void*)gp,
                (__attribute__((address_space(3))) void*)(&As[q * 8]), 16, 0, 0);
        }
#pragma unroll
        for (int i = 0; i < 4; ++i) {
            int q   = i * 256 + tid;
            int r   = q >> 3;
            int cbg = (q & 7) ^ (r & 7);
            const unsigned short* gp = Bt + (size_t)(nBase + r) * Kp + k0 + cbg * 8;
            __builtin_amdgcn_global_load_lds(
                (const __attribute__((address_space(1))) void*)gp,
                (__attribute__((address_space(3))) void*)(&Bs[q * 8]), 16, 0, 0);
        }
        __syncthreads();
#pragma unroll
        for (int kk = 0; kk < 2; ++kk) {
            bf16x8 a[4], b[4];
            const int cb = kk * 4 + (lane >> 4);
#pragma unroll
            for (int i = 0; i < 4; ++i) {
                int r = wm * 64 + i * 16 + (lane & 15);
                a[i] = *(const bf16x8*)&As[(r * 8 + (cb ^ (r & 7))) * 8];
            }
#pragma unroll
            for (int j = 0; j < 4; ++j) {
                int r = wn * 64 + j * 16 + (lane & 15);
                b[j] = *(const bf16x8*)&Bs[(r * 8 + (cb ^ (r & 7))) * 8];
            }
#pragma unroll
            for (int i = 0; i < 4; ++i)
#pragma unroll
                for (int j = 0; j < 4; ++j)
                    acc[i][j] = __builtin_amdgcn_mfma_f32_16x16x32_bf16(b[j], a[i], acc[i][j], 0, 0, 0);
        }
    }

    const int quad = lane >> 4;
#pragma unroll
    for (int i = 0; i < 4; ++i) {
        int row = rowBase + wm * 64 + i * 16 + (lane & 15);
        if (row >= Nrows) continue;
        float sc = 1.f;
        if (DEGB) sc = 1.f + (float)deg[row];
#pragma unroll
        for (int j = 0; j < 4; ++j) {
            int colb = nBase + wn * 64 + j * 16 + quad * 4;
            float4 bv = (colb < Mvalid) ? *(const float4*)(bias + colb)
                                        : (float4){0.f, 0.f, 0.f, 0.f};
            float v0 = acc[i][j][0] + sc * bv.x;
            float v1 = acc[i][j][1] + sc * bv.y;
            float v2 = acc[i][j][2] + sc * bv.z;
            float v3 = acc[i][j][3] + sc * bv.w;
            if (RELU) {
                v0 = v0 > 0.f ? v0 : 0.f; v1 = v1 > 0.f ? v1 : 0.f;
                v2 = v2 > 0.f ? v2 : 0.f; v3 = v3 > 0.f ? v3 : 0.f;
            }
            if (OUT_BF) {
                ushort4 o; o.x = f2bf(v0); o.y = f2bf(v1); o.z = f2bf(v2); o.w = f2bf(v3);
                *(ushort4*)(outB + (size_t)row * Mp + colb) = o;
            }
            if (OUT_F32) {
                if (colb < Mvalid)
                    *(float4*)(outF + (size_t)row * Mvalid + colb) = (float4){v0, v1, v2, v3};
            }
        }
    }
}

template <bool RELU, bool OUT_BF, bool OUT_F32, bool DEGB, int MT>
__global__ __launch_bounds__(256, 4) void rg_gemm(
    const unsigned short* __restrict__ A, const unsigned short* __restrict__ Bt,
    const float* __restrict__ bias, const int* __restrict__ deg, int Mvalid,
    unsigned short* __restrict__ outB, float* __restrict__ outF,
    int Nrows, int Kp, int Mp, int gN)
{
    gemm_body<RELU, OUT_BF, OUT_F32, DEGB, MT>(blockIdx.x, A, Bt, bias, deg,
                                               Mvalid, outB, outF, Nrows, Kp, Mp, gN);
}

// ---------------- 64x128 GEMM body (latency-bound layers) -------------------
// 4 waves as 1x4: wave w covers cols [w*32, +32), all 64 rows; acc[4][2].
// LDS 24KB. Doubles block count vs 128-row tile -> more waves to hide the
// barrier-drain latency at small K.
template <bool RELU, bool OUT_BF, bool OUT_F32, bool DEGB, int MT>
__global__ __launch_bounds__(256, 4) void rg_gemm64(
    const unsigned short* __restrict__ A, const unsigned short* __restrict__ Bt,
    const float* __restrict__ bias, const int* __restrict__ deg, int Mvalid,
    unsigned short* __restrict__ outB, float* __restrict__ outF,
    int Nrows, int Kp, int Mp, int gN64)
{
    __shared__ __align__(16) unsigned short As[64 * 64];
    __shared__ __align__(16) unsigned short Bs[128 * 64];

    int bid = blockIdx.x;
    int xcd = bid & 7;
    int slot = bid >> 3;
    int c = slot % MT;
    int rsub = slot / MT;
    int rt = rsub * 8 + xcd;
    if (rt >= gN64) return;
    const int rowBase = rt * 64;
    const int nBase   = c * 128;

    const int tid  = threadIdx.x;
    const int lane = tid & 63;
    const int wn   = tid >> 6;

    f32x4 acc[4][2];
#pragma unroll
    for (int i = 0; i < 4; ++i)
#pragma unroll
        for (int j = 0; j < 2; ++j) acc[i][j] = (f32x4){0.f, 0.f, 0.f, 0.f};

    const int nkt = Kp >> 6;
    for (int kt = 0; kt < nkt; ++kt) {
        __syncthreads();
        const int k0 = kt * 64;
#pragma unroll
        for (int i = 0; i < 2; ++i) {
            int q   = i * 256 + tid;
            int r   = q >> 3;
            int cbg = (q & 7) ^ (r & 7);
            const unsigned short* gp = A + (size_t)(rowBase + r) * Kp + k0 + cbg * 8;
            __builtin_amdgcn_global_load_lds(
                (const __attribute__((address_space(1))) void*)gp,
                (__attribute__((address_space(3))) void*)(&As[q * 8]), 16, 0, 0);
        }
#pragma unroll
        for (int i = 0; i < 4; ++i) {
            int q   = i * 256 + tid;
            int r   = q >> 3;
            int cbg = (q & 7) ^ (r & 7);
            const unsigned short* gp = Bt + (size_t)(nBase + r) * Kp + k0 + cbg * 8;
            __builtin_amdgcn_global_load_lds(
                (const __attribute__((address_space(1))) void*)gp,
                (__attribute__((address_space(3))) void*)(&Bs[q * 8]), 16, 0, 0);
        }
        __syncthreads();
#pragma unroll
        for (int kk = 0; kk < 2; ++kk) {
            bf16x8 a[4], b[2];
            const int cb = kk * 4 + (lane >> 4);
#pragma unroll
            for (int i = 0; i < 4; ++i) {
                int r = i * 16 + (lane & 15);
                a[i] = *(const bf16x8*)&As[(r * 8 + (cb ^ (r & 7))) * 8];
            }
#pragma unroll
            for (int j = 0; j < 2; ++j) {
                int r = wn * 32 + j * 16 + (lane & 15);
                b[j] = *(const bf16x8*)&Bs[(r * 8 + (cb ^ (r & 7))) * 8];
            }
#pragma unroll
            for (int i = 0; i < 4; ++i)
#pragma unroll
                for (int j = 0; j < 2; ++j)
                    acc[i][j] = __builtin_amdgcn_mfma_f32_16x16x32_bf16(b[j], a[i], acc[i][j], 0, 0, 0);
        }
    }

    const int quad = lane >> 4;
#pragma unroll
    for (int i = 0; i < 4; ++i) {
        int row = rowBase + i * 16 + (lane & 15);
        if (row >= Nrows) continue;
        float sc = 1.f;
        if (DEGB) sc = 1.f + (float)deg[row];
#pragma unroll
        for (int j = 0; j < 2; ++j) {
            int colb = nBase + wn * 32 + j * 16 + quad * 4;
            float4 bv = (colb < Mvalid) ? *(const float4*)(bias + colb)
                                        : (float4){0.f, 0.f, 0.f, 0.f};
            float v0 = acc[i][j][0] + sc * bv.x;
            float v1 = acc[i][j][1] + sc * bv.y;
            float v2 = acc[i][j][2] + sc * bv.z;
            float v3 = acc[i][j][3] + sc * bv.w;
            if (RELU) {
                v0 = v0 > 0.f ? v0 : 0.f; v1 = v1 > 0.f ? v1 : 0.f;
                v2 = v2 > 0.f ? v2 : 0.f; v3 = v3 > 0.f ? v3 : 0.f;
            }
            if (OUT_BF) {
                ushort4 o; o.x = f2bf(v0); o.y = f2bf(v1); o.z = f2bf(v2); o.w = f2bf(v3);
                *(ushort4*)(outB + (size_t)row * Mp + colb) = o;
            }
            if (OUT_F32) {
                if (colb < Mvalid)
                    *(float4*)(outF + (size_t)row * Mvalid + colb) = (float4){v0, v1, v2, v3};
            }
        }
    }
}

// L1 GEMM + edge scatter in one dispatch (trailing layout, atomic-free)
__global__ __launch_bounds__(256, 4) void rg_gemm_l1_scatter(
    const unsigned short* __restrict__ A, const unsigned short* __restrict__ Bt,
    const float* __restrict__ bias, int Mvalid,
    unsigned short* __restrict__ outB, int Nrows, int Kp, int Mp, int gN,
    int gemmBlocks, const int* __restrict__ ei, int E,
    const int* __restrict__ rowptr, const int* __restrict__ rank,
    int* __restrict__ cols)
{
    int bid = blockIdx.x;
    if (bid < gemmBlocks) {
        gemm_body<true, true, false, false, 8>(bid, A, Bt, bias, nullptr,
                                               Mvalid, outB, nullptr, Nrows, Kp, Mp, gN);
    } else {
        int e = (bid - gemmBlocks) * 256 + threadIdx.x;
        if (e < E) {
            int d = ei[E + e];
            int p = rowptr[d] + rank[e];
            cols[p] = ei[e];
        }
    }
}

// ---------------- merged scan (wave-shuffle stage 1) ------------------------
__device__ __forceinline__ void rg_gridbar(int* bar, int nb, int phase) {
    __syncthreads();
    if (threadIdx.x == 0) {
        __threadfence();
        atomicAdd(bar, 1);
        int target = phase * nb;
        while (__hip_atomic_load(bar, __ATOMIC_RELAXED, __HIP_MEMORY_SCOPE_AGENT) < target) {}
        __threadfence();
    }
    __syncthreads();
}

__global__ __launch_bounds__(1024) void rg_scan_all(
    const int* __restrict__ cnt, int* __restrict__ rowptr,
    int* __restrict__ bsums, int* bar, int Nn, int E, int nb)
{
    __shared__ int wsums[16];
    const int tid = threadIdx.x;
    const int bid = blockIdx.x;
    const int i   = bid * 1024 + tid;
    const int lane = tid & 63;
    const int wid  = tid >> 6;

    // stage 1: wave-shuffle inclusive scan + 16-wave combine (2 barriers)
    int v = (i < Nn) ? cnt[i] : 0;
    int incl = v;
#pragma unroll
    for (int off = 1; off < 64; off <<= 1) {
        int t = __shfl_up(incl, off, 64);
        if (lane >= off) incl += t;
    }
    if (lane == 63) wsums[wid] = incl;
    __syncthreads();
    if (tid < 16) {
        int wv = wsums[tid];
        int wi = wv;
#pragma unroll
        for (int off = 1; off < 16; off <<= 1) {
            int t = __shfl_up(wi, off, 64);
            if (tid >= off) wi += t;
        }
        wsums[tid] = wi - wv;   // exclusive wave offset
    }
    __syncthreads();
    int blockIncl = incl + wsums[wid];   // block-inclusive prefix at tid
    if (tid == 1023) bsums[bid] = blockIncl;
    rg_gridbar(bar, nb, 1);

    // stage 2: exclusive wave-scan of block sums (block 0, nb <= 64)
    if (bid == 0 && tid < 64) {
        int bv = (tid < nb) ? bsums[tid] : 0;
        int bi2 = bv;
#pragma unroll
        for (int off = 1; off < 64; off <<= 1) {
            int t = __shfl_up(bi2, off, 64);
            if (tid >= off) bi2 += t;
        }
        if (tid < nb) bsums[tid] = bi2 - bv;   // exclusive
    }
    rg_gridbar(bar, nb, 2);

    // stage 3: write rowptr
    if (i < Nn) {
        rowptr[i] = blockIncl - v + bsums[bid];
    }
    if (i == 0) rowptr[Nn] = E;
}

// ---------------- 80-dim aggregation: s[i] = pf[i] + sum_{src->i} pf[src] --
// pf is [Npad,128] bf16 with cols 80..127 == 0 (W4t zero-padded). Gather
// loads masked to lanes 0..39 (40 uints = 80 cols): 4 -> 3 cache lines per
// edge row. Writes keep all 64 lanes (s cols 80..127 must be zero for L5).
__global__ __launch_bounds__(256) void rg_agg80(
    const unsigned short* __restrict__ pf, const int* __restrict__ rowptr,
    const int* __restrict__ cols, unsigned short* __restrict__ s, int Nn)
{
    int node = blockIdx.x * 4 + (threadIdx.x >> 6);
    if (node >= Nn) return;
    int lane = threadIdx.x & 63;
    const bool act = lane < 40;
    const unsigned* xp = (const unsigned*)pf;   // 64 uints per row
    size_t off = (size_t)node * 64 + lane;
    float a0 = 0.f, a1 = 0.f;
    if (act) {
        unsigned u = xp[off];
        a0 = bf2f(u & 0xffffu); a1 = bf2f(u >> 16);
    }
    int beg = rowptr[node], end = rowptr[node + 1];
    int e = beg;
    for (; e + 8 <= end; e += 8) {
        unsigned v[8];
        if (act) {
#pragma unroll
            for (int t = 0; t < 8; ++t) v[t] = xp[(size_t)cols[e + t] * 64 + lane];
#pragma unroll
            for (int t = 0; t < 8; ++t) { a0 += bf2f(v[t] & 0xffffu); a1 += bf2f(v[t] >> 16); }
        }
    }
    for (; e < end; ++e) {
        if (act) {
            unsigned v = xp[(size_t)cols[e] * 64 + lane];
            a0 += bf2f(v & 0xffffu); a1 += bf2f(v >> 16);
        }
    }
    unsigned o = act ? ((unsigned)f2bf(a0) | ((unsigned)f2bf(a1) << 16)) : 0u;
    ((unsigned*)s)[off] = o;
}

// ---------------------------------------------------------------------------
extern "C" void kernel_launch(void* const* d_in, const int* in_sizes, int n_in,
                              void* d_out, int out_size, void* d_ws, size_t ws_size,
                              hipStream_t stream)
{
    const float* feat = (const float*)d_in[0];
    const int*   ei   = (const int*)d_in[1];
    const float* W1 = (const float*)d_in[2];  const float* b1 = (const float*)d_in[3];
    const float* W2 = (const float*)d_in[4];  const float* b2 = (const float*)d_in[5];
    const float* W3 = (const float*)d_in[6];  const float* b3 = (const float*)d_in[7];
    const float* W4 = (const float*)d_in[8];  const float* b4 = (const float*)d_in[9];
    const float* Wi = (const float*)d_in[10]; const float* bi = (const float*)d_in[11];
    const float* Wg1 = (const float*)d_in[12]; const float* bg1 = (const float*)d_in[13];
    const float* Wg2 = (const float*)d_in[14]; const float* bg2 = (const float*)d_in[15];
    const float* Wo = (const float*)d_in[16]; const float* bo = (const float*)d_in[17];

    const int N = in_sizes[0] / 512;   // 50000
    const int E = in_sizes[1] / 2;     // 800000
    const int gN = (N + 127) / 128;    // 391
    const int Npad = gN * 128;         // 50048

    char* ws = (char*)d_ws;
    size_t o = 0;
    auto alloc = [&](size_t bytes) { char* p = ws + o; o += (bytes + 255) & ~(size_t)255; return p; };
    unsigned short* bufA = (unsigned short*)alloc((size_t)Npad * 1024 * 2); // h1 / pf / g
    unsigned short* bufB = (unsigned short*)alloc((size_t)Npad * 1024 * 2); // h2 / r1
    unsigned short* bufC = (unsigned short*)alloc((size_t)Npad * 512 * 2);  // A0 / h3 / s / g2
    unsigned short* W1t = (unsigned short*)alloc((size_t)1024 * 512 * 2);
    unsigned short* W2t = (unsigned short*)alloc((size_t)1024 * 1024 * 2);
    unsigned short* W3t = (unsigned short*)alloc((size_t)512 * 1024 * 2);
    unsigned short* W4t = (unsigned short*)alloc((size_t)128 * 512 * 2);
    unsigned short* Wit = (unsigned short*)alloc((size_t)512 * 128 * 2);
    unsigned short* Wg1t = (unsigned short*)alloc((size_t)512 * 512 * 2);
    unsigned short* Wg2t = (unsigned short*)alloc((size_t)512 * 512 * 2);
    unsigned short* Wot = (unsigned short*)alloc((size_t)128 * 512 * 2);
    int* cnt    = (int*)alloc((size_t)(N + 64) * 4);
    int* bar    = cnt + N;
    int* rowptr = (int*)alloc((size_t)(N + 1) * 4);
    int* rank   = (int*)alloc((size_t)E * 4);
    int* cols   = (int*)alloc((size_t)E * 4);
    int* bsums  = (int*)alloc(256);

    float* out_mask = (float*)d_out;                  // [N,80]
    float* out_feat = (float*)d_out + (size_t)N * 80; // [N,80]

    // ---- merged preprocessing ----
    hipMemsetAsync(cnt, 0, (size_t)(N + 64) * 4, stream);
    {
        PreDescs d;
        const float* Ws[8]  = {W1, W2, W3, W4, Wi, Wg1, Wg2, Wo};
        unsigned short* Ts[8] = {W1t, W2t, W3t, W4t, Wit, Wg1t, Wg2t, Wot};
        int Ks[8]  = {512, 1024, 1024, 512, 80, 512, 512, 512};
        int Ms[8]  = {1024, 1024, 512, 80, 512, 512, 512, 80};
        int Kps[8] = {512, 1024, 1024, 512, 128, 512, 512, 512};
        int Mps[8] = {1024, 1024, 512, 128, 512, 512, 512, 128};
        int st = 0;
        for (int i = 0; i < 8; ++i) {
            d.W[i] = Ws[i]; d.Wt[i] = Ts[i];
            d.K[i] = Ks[i]; d.M[i] = Ms[i]; d.Kp[i] = Kps[i];
            d.ntx[i] = Mps[i] / 32;
            d.start[i] = st;
            st += (Mps[i] / 32) * (Kps[i] / 32);
        }
        d.tEnd = st;
        d.cEnd = st + (N * 512) / 4096;
        d.eEnd = d.cEnd + (E + 1023) / 1024;
        d.feat = feat; d.featb = bufC; d.nFeat = N * 512;
        d.ei = ei; d.E = E; d.cnt = cnt; d.rank = rank;
        rg_preprocess<<<d.eEnd, 256, 0, stream>>>(d);
    }

    // ---- CSR scan ----
    const int nb = (N + 1023) / 1024;   // 49
    rg_scan_all<<<nb, 1024, 0, stream>>>(cnt, rowptr, bsums, bar, N, E, nb);

    const int rg8 = ((gN + 7) / 8) * 8;      // 392
    auto grid = [&](int MT) { return dim3(rg8 * MT); };
    const int gN64 = (N + 63) / 64;          // 782
    const int rg64 = ((gN64 + 7) / 8) * 8;   // 784

    // L1: h1 = relu(A0 @ W1 + b1)   [N,1024]  + atomic-free scatter trailing
    {
        const int gemmBlocks = rg8 * 8;             // 3136
        const int scatBlocks = (E + 255) / 256;     // 3125
        rg_gemm_l1_scatter<<<dim3(gemmBlocks + scatBlocks), 256, 0, stream>>>(
            bufC, W1t, b1, 1024, bufA, N, 512, 1024, gN,
            gemmBlocks, ei, E, rowptr, rank, cols);
    }

    // L2: h2 = relu(h1 @ W2 + b2)   [N,1024]
    rg_gemm<true, true, false, false, 8><<<grid(8), 256, 0, stream>>>(bufA, W2t, b2, nullptr, 1024, bufB, nullptr, N, 1024, 1024, gN);
    // L3: h3 = relu(h2 @ W3 + b3)   [N,512]
    rg_gemm<true, true, false, false, 4><<<grid(4), 256, 0, stream>>>(bufB, W3t, b3, nullptr, 512, bufC, nullptr, N, 1024, 512, gN);
    // L4: pf = h3 @ W4 + b4  -> fp32 out_feat + bf16 padded [N,128]  (64-row)
    rg_gemm64<false, true, true, false, 1><<<dim3(rg64), 256, 0, stream>>>(bufC, W4t, b4, nullptr, 80, bufA, out_feat, N, 512, 128, gN64);

    // 80-dim aggregation (lane-masked gather): s -> bufC[:, :128]
    rg_agg80<<<(N + 3) / 4, 256, 0, stream>>>(bufA, rowptr, cols, bufC, N);

    // L5: g = s @ Win + (1+deg)*bin  [N,512]   (64-row body, K=128)
    rg_gemm64<false, true, false, true, 4><<<dim3(rg64 * 4), 256, 0, stream>>>(bufC, Wit, bi, cnt, 512, bufA, nullptr, N, 128, 512, gN64);

    // L6: r1 = relu(g @ Wg1 + bg1)  [N,512]
    rg_gemm<true, true, false, false, 4><<<grid(4), 256, 0, stream>>>(bufA, Wg1t, bg1, nullptr, 512, bufB, nullptr, N, 512, 512, gN);
    // L7: g2 = r1 @ Wg2 + bg2       [N,512]
    rg_gemm<false, true, false, false, 4><<<grid(4), 256, 0, stream>>>(bufB, Wg2t, bg2, nullptr, 512, bufC, nullptr, N, 512, 512, gN);
    // L8: mask = g2 @ Wout + bout -> fp32 out_mask   (64-row)
    rg_gemm64<false, false, true, false, 1><<<dim3(rg64), 256, 0, stream>>>(bufC, Wot, bo, nullptr, 80, nullptr, out_mask, N, 512, 128, gN64);
}